// Round 3
// baseline (621.988 us; speedup 1.0000x reference)
//
#include <hip/hip_runtime.h>
#include <hip/hip_bf16.h>
#include <hip/hip_fp16.h>

typedef __hip_bfloat16 bf16;
typedef __attribute__((ext_vector_type(8))) __bf16 bf16x8;   // MFMA A/B frag (4 VGPRs)
typedef __attribute__((ext_vector_type(4))) float floatx4;   // MFMA C/D frag
typedef __attribute__((ext_vector_type(8))) ushort ushortx8; // 16B of 2B elems

#define TILE 128
#define BK 32
#define LDS_STRIDE 40  // 32 + 8 pad: 80B rows keep 16B alignment, break b128 bank aliasing

__device__ inline ushort f2bf(float f) {
    bf16 h = __float2bfloat16(f);
    ushort u; __builtin_memcpy(&u, &h, 2); return u;
}
__device__ inline float bf2f(ushort u) {
    unsigned v = ((unsigned)u) << 16;
    float f; __builtin_memcpy(&f, &v, 4); return f;
}
__device__ inline ushort f2h(float f) {
    __half h = __float2half(f);
    ushort u; __builtin_memcpy(&u, &h, 2); return u;
}
__device__ inline float h2f(ushort u) {
    __half h; __builtin_memcpy(&h, &u, 2);
    return __half2float(h);
}

// C[m][n] = scale * sum_k A[m][k]*B[n][k] (+ bias[n])   -- "NT" GEMM, bf16 MFMA.
// AM/BM operand mode: 0 = bf16 rows, 1 = fp32 rows (cvt to bf16 in staging),
//                     2 = fp32 rows SPLIT hi/lo (3 MFMAs -> ~fp32 product precision).
// OM output mode: 0 = fp32, 1 = bf16, 2 = fp16 (stores scale*acc+bias).
// TRANS: store C[n*ldc+m] (builds vp^T). HB: fp32 bias pointer.
template<int AM, int BM, int OM, bool TRANS, bool HB>
__global__ __launch_bounds__(256)
void gemm_nt(const void* __restrict__ A, long long batchA, int lda,
             const void* __restrict__ B, long long batchB, int ldb,
             void* __restrict__ C, long long batchC, int ldc,
             const float* __restrict__ bias, float scale, int K)
{
    constexpr int APL = (AM == 2) ? 2 : 1;
    constexpr int BPL = (BM == 2) ? 2 : 1;
    __shared__ ushort As[APL * TILE * LDS_STRIDE];
    __shared__ ushort Bs[BPL * TILE * LDS_STRIDE];

    const int bz    = blockIdx.z;
    const int tileM = blockIdx.y * TILE;
    const int tileN = blockIdx.x * TILE;

    const int t    = threadIdx.x;
    const int lane = t & 63;
    const int wave = t >> 6;
    const int wr   = (wave >> 1) * 64;
    const int wc   = (wave & 1) * 64;
    const int lrow = lane & 15;
    const int kq   = (lane >> 4) * 8;

    floatx4 acc[4][4];
#pragma unroll
    for (int i = 0; i < 4; i++)
#pragma unroll
        for (int j = 0; j < 4; j++) acc[i][j] = (floatx4){0.f, 0.f, 0.f, 0.f};

    for (int k0 = 0; k0 < K; k0 += BK) {
        // stage 128x32 tiles: 512 8-elem chunks each, 2 per thread per operand
#pragma unroll
        for (int c = t; c < 512; c += 256) {
            const int r   = c >> 2;
            const int col = (c & 3) * 8;
            // ---- A ----
            if (AM == 0) {
                const ushort* Ab = (const ushort*)A + (size_t)bz * batchA;
                *(floatx4*)(&As[r * LDS_STRIDE + col]) =
                    *(const floatx4*)(Ab + (size_t)(tileM + r) * lda + k0 + col);
            } else {
                const float* Af = (const float*)A + (size_t)bz * batchA;
                const float* src = Af + (size_t)(tileM + r) * lda + k0 + col;
                floatx4 f0 = *(const floatx4*)src, f1 = *(const floatx4*)(src + 4);
                float f[8] = {f0.x, f0.y, f0.z, f0.w, f1.x, f1.y, f1.z, f1.w};
                ushortx8 hi;
#pragma unroll
                for (int i = 0; i < 8; i++) hi[i] = f2bf(f[i]);
                *(ushortx8*)(&As[r * LDS_STRIDE + col]) = hi;
                if (AM == 2) {
                    ushortx8 lo;
#pragma unroll
                    for (int i = 0; i < 8; i++) lo[i] = f2bf(f[i] - bf2f(hi[i]));
                    *(ushortx8*)(&As[TILE * LDS_STRIDE + r * LDS_STRIDE + col]) = lo;
                }
            }
            // ---- B ----
            if (BM == 0) {
                const ushort* Bb = (const ushort*)B + (size_t)bz * batchB;
                *(floatx4*)(&Bs[r * LDS_STRIDE + col]) =
                    *(const floatx4*)(Bb + (size_t)(tileN + r) * ldb + k0 + col);
            } else {
                const float* Bf = (const float*)B + (size_t)bz * batchB;
                const float* src = Bf + (size_t)(tileN + r) * ldb + k0 + col;
                floatx4 f0 = *(const floatx4*)src, f1 = *(const floatx4*)(src + 4);
                float f[8] = {f0.x, f0.y, f0.z, f0.w, f1.x, f1.y, f1.z, f1.w};
                ushortx8 hi;
#pragma unroll
                for (int i = 0; i < 8; i++) hi[i] = f2bf(f[i]);
                *(ushortx8*)(&Bs[r * LDS_STRIDE + col]) = hi;
                if (BM == 2) {
                    ushortx8 lo;
#pragma unroll
                    for (int i = 0; i < 8; i++) lo[i] = f2bf(f[i] - bf2f(hi[i]));
                    *(ushortx8*)(&Bs[TILE * LDS_STRIDE + r * LDS_STRIDE + col]) = lo;
                }
            }
        }
        __syncthreads();

        bf16x8 aH[4], bH[4], aL[4], bL[4];
#pragma unroll
        for (int i = 0; i < 4; i++) {
            aH[i] = *(const bf16x8*)(&As[(wr + i * 16 + lrow) * LDS_STRIDE + kq]);
            bH[i] = *(const bf16x8*)(&Bs[(wc + i * 16 + lrow) * LDS_STRIDE + kq]);
            if (AM == 2)
                aL[i] = *(const bf16x8*)(&As[TILE * LDS_STRIDE + (wr + i * 16 + lrow) * LDS_STRIDE + kq]);
            if (BM == 2)
                bL[i] = *(const bf16x8*)(&Bs[TILE * LDS_STRIDE + (wc + i * 16 + lrow) * LDS_STRIDE + kq]);
        }
#pragma unroll
        for (int i = 0; i < 4; i++)
#pragma unroll
            for (int j = 0; j < 4; j++) {
                acc[i][j] = __builtin_amdgcn_mfma_f32_16x16x32_bf16(aH[i], bH[j], acc[i][j], 0, 0, 0);
                if (AM == 2)
                    acc[i][j] = __builtin_amdgcn_mfma_f32_16x16x32_bf16(aL[i], bH[j], acc[i][j], 0, 0, 0);
                if (BM == 2)
                    acc[i][j] = __builtin_amdgcn_mfma_f32_16x16x32_bf16(aH[i], bL[j], acc[i][j], 0, 0, 0);
            }
        __syncthreads();
    }

    // epilogue: C/D layout col=lane&15, row=(lane>>4)*4+reg
    const int rq = (lane >> 4) * 4;
#pragma unroll
    for (int i = 0; i < 4; i++) {
#pragma unroll
        for (int j = 0; j < 4; j++) {
            const int gn = tileN + wc + j * 16 + lrow;
            const float bv = HB ? bias[gn] : 0.f;
#pragma unroll
            for (int r = 0; r < 4; r++) {
                const int gm = tileM + wr + i * 16 + rq + r;
                const float val = acc[i][j][r] * scale + bv;
                const size_t idx = TRANS ? ((size_t)gn * ldc + gm) : ((size_t)gm * ldc + gn);
                if (OM == 0) {
                    float* Cf = (float*)C + (size_t)bz * batchC;
                    Cf[idx] = val;
                } else if (OM == 1) {
                    bf16* Cb = (bf16*)C + (size_t)bz * batchC;
                    Cb[idx] = __float2bfloat16(val);
                } else {
                    ushort* Ch = (ushort*)C + (size_t)bz * batchC;
                    Ch[idx] = f2h(val);
                }
            }
        }
    }
}

// Row softmax over S=2048 fp16 (pre-scaled) logits; fp32 math; writes bf16
// probs IN PLACE (same 2B slots). All global reads precede the first
// __syncthreads; all writes follow the last -> no aliasing hazard.
__global__ __launch_bounds__(256)
void softmax_rows(ushort* __restrict__ scores)
{
    const int S = 2048;
    ushort* srow = scores + (size_t)blockIdx.x * S;
    const int t    = threadIdx.x;
    const int lane = t & 63;
    const int w    = t >> 6;

    ushortx8 raw = *(const ushortx8*)(srow + t * 8);
    float l[8];
#pragma unroll
    for (int i = 0; i < 8; i++) l[i] = h2f(raw[i]);

    float m = l[0];
#pragma unroll
    for (int i = 1; i < 8; i++) m = fmaxf(m, l[i]);
#pragma unroll
    for (int off = 32; off >= 1; off >>= 1) m = fmaxf(m, __shfl_down(m, off));

    __shared__ float redm[4], reds[4];
    if (lane == 0) redm[w] = m;
    __syncthreads();
    m = fmaxf(fmaxf(redm[0], redm[1]), fmaxf(redm[2], redm[3]));

    float e[8], s = 0.f;
#pragma unroll
    for (int i = 0; i < 8; i++) { e[i] = __expf(l[i] - m); s += e[i]; }
#pragma unroll
    for (int off = 32; off >= 1; off >>= 1) s += __shfl_down(s, off);
    if (lane == 0) reds[w] = s;
    __syncthreads();
    s = reds[0] + reds[1] + reds[2] + reds[3];
    const float inv = 1.f / s;

    ushortx8 o;
#pragma unroll
    for (int i = 0; i < 8; i++) o[i] = f2bf(e[i] * inv);
    *(ushortx8*)(srow + t * 8) = o;
}

extern "C" void kernel_launch(void* const* d_in, const int* in_sizes, int n_in,
                              void* d_out, int out_size, void* d_ws, size_t ws_size,
                              hipStream_t stream)
{
    const int B = 4, S = 2048, D = 1024;
    const float* q  = (const float*)d_in[0];
    const float* k  = (const float*)d_in[1];
    const float* v  = (const float*)d_in[2];
    const float* Wq = (const float*)d_in[3];
    const float* bq = (const float*)d_in[4];
    const float* Wk = (const float*)d_in[5];
    const float* bk = (const float*)d_in[6];
    const float* Wv = (const float*)d_in[7];
    const float* bv = (const float*)d_in[8];
    const float* Wo = (const float*)d_in[9];
    const float* bo = (const float*)d_in[10];
    float* out = (float*)d_out;

    // ws: qp fp32 32MB | kp fp32 32MB | scores fp16 32MB  = 96 MB total.
    // Reuse: vpt (bf16, 16MB) overlays qp after QK^T; attn (bf16, 16MB) overlays kp.
    float* qp = (float*)d_ws;
    float* kp = qp + (size_t)B * S * D;
    ushort* sc = (ushort*)(kp + (size_t)B * S * D);  // fp16 scaled logits -> bf16 probs
    bf16* vpt  = (bf16*)qp;                          // per batch: [D][S]
    bf16* attn = (bf16*)kp;                          // [B*S][D] contiguous

    dim3 blk(256);

    // qp = q @ Wq^T + bq  (split x split -> ~fp32 precision, fp32 out)
    gemm_nt<2, 2, 0, false, true><<<dim3(D / TILE, (B * S) / TILE, 1), blk, 0, stream>>>(
        q, 0, D, Wq, 0, D, qp, 0, D, bq, 1.0f, D);
    // kp = k @ Wk^T + bk
    gemm_nt<2, 2, 0, false, true><<<dim3(D / TILE, (B * S) / TILE, 1), blk, 0, stream>>>(
        k, 0, D, Wk, 0, D, kp, 0, D, bk, 1.0f, D);
    // scores = 0.125 * qp @ kp^T  (split x split, fp16 out, pre-scaled)
    gemm_nt<2, 2, 2, false, false><<<dim3(S / TILE, S / TILE, B), blk, 0, stream>>>(
        qp, (long long)S * D, D, kp, (long long)S * D, D,
        sc, (long long)S * S, S, nullptr, 0.125f, D);
    // vpt = (v @ Wv^T + bv)^T per batch  (plain bf16; overlays dead qp)
    gemm_nt<1, 1, 1, true, true><<<dim3(D / TILE, S / TILE, B), blk, 0, stream>>>(
        v, (long long)S * D, D, Wv, 0, D, vpt, (long long)D * S, S, bv, 1.0f, D);
    // probs = softmax(scores) in place (bf16)
    softmax_rows<<<dim3(B * S), blk, 0, stream>>>(sc);
    // attn = probs @ vp  (bf16 x bf16 -> bf16; overlays dead kp)
    gemm_nt<0, 0, 1, false, false><<<dim3(D / TILE, S / TILE, B), blk, 0, stream>>>(
        sc, (long long)S * S, S, vpt, (long long)D * S, S,
        attn, (long long)S * D, D, nullptr, 1.0f, S);
    // out = attn @ Wo^T + bo  (bf16 x cvt(Wo) -> fp32)
    gemm_nt<0, 1, 0, false, true><<<dim3(D / TILE, (B * S) / TILE, 1), blk, 0, stream>>>(
        attn, 0, D, Wo, 0, D, out, 0, D, bo, 1.0f, D);
}

// Round 4
// 483.826 us; speedup vs baseline: 1.2856x; 1.2856x over previous
//
#include <hip/hip_runtime.h>
#include <hip/hip_fp16.h>

typedef __attribute__((ext_vector_type(8))) _Float16 half8;  // MFMA A/B frag (4 VGPRs)
typedef __attribute__((ext_vector_type(4))) float floatx4;   // MFMA C/D frag
typedef __attribute__((ext_vector_type(8))) ushort ushortx8; // 16B of fp16 bits

#define TILE 128
#define BK 32
#define LDS_STRIDE 40  // 32 + 8 pad: 80B rows keep 16B alignment, break b128 bank aliasing

__device__ inline ushort f2h(float f) {
    _Float16 h = (_Float16)f;
    ushort u; __builtin_memcpy(&u, &h, 2); return u;
}
__device__ inline float h2f(ushort u) {
    _Float16 h; __builtin_memcpy(&h, &u, 2);
    return (float)h;
}

// C[m][n] = scale * sum_k A[m][k]*B[n][k] (+ bias[n])   -- "NT" GEMM, fp16 MFMA.
// AM: 0 = A is fp16 rows, 1 = A is fp32 rows (cvt to fp16 during LDS staging).
// B: always fp16 rows. OM: 0 = fp32 store, 1 = fp16 store (scale*acc+bias).
// TRANS: store C[n*ldc+m] (builds vp^T). HB: fp32 bias.
template<int AM, int OM, bool TRANS, bool HB>
__global__ __launch_bounds__(256)
void gemm_nt(const void* __restrict__ A, long long batchA, int lda,
             const ushort* __restrict__ B, long long batchB, int ldb,
             void* __restrict__ C, long long batchC, int ldc,
             const float* __restrict__ bias, float scale, int K)
{
    __shared__ ushort As[TILE * LDS_STRIDE];
    __shared__ ushort Bs[TILE * LDS_STRIDE];

    const int bz    = blockIdx.z;
    const int tileM = blockIdx.y * TILE;
    const int tileN = blockIdx.x * TILE;
    const ushort* Bb = B + (size_t)bz * batchB;

    const int t    = threadIdx.x;
    const int lane = t & 63;
    const int wave = t >> 6;
    const int wr   = (wave >> 1) * 64;
    const int wc   = (wave & 1) * 64;
    const int lrow = lane & 15;
    const int kq   = (lane >> 4) * 8;

    floatx4 acc[4][4];
#pragma unroll
    for (int i = 0; i < 4; i++)
#pragma unroll
        for (int j = 0; j < 4; j++) acc[i][j] = (floatx4){0.f, 0.f, 0.f, 0.f};

    for (int k0 = 0; k0 < K; k0 += BK) {
        // stage 128x32 A/B tiles: 512 8-elem chunks each, 2 per thread per operand
#pragma unroll
        for (int c = t; c < 512; c += 256) {
            const int r   = c >> 2;
            const int col = (c & 3) * 8;
            if (AM == 0) {
                const ushort* Ab = (const ushort*)A + (size_t)bz * batchA;
                *(ushortx8*)(&As[r * LDS_STRIDE + col]) =
                    *(const ushortx8*)(Ab + (size_t)(tileM + r) * lda + k0 + col);
            } else {
                const float* Af = (const float*)A + (size_t)bz * batchA;
                const float* src = Af + (size_t)(tileM + r) * lda + k0 + col;
                floatx4 f0 = *(const floatx4*)src, f1 = *(const floatx4*)(src + 4);
                ushortx8 u;
                u[0] = f2h(f0.x); u[1] = f2h(f0.y); u[2] = f2h(f0.z); u[3] = f2h(f0.w);
                u[4] = f2h(f1.x); u[5] = f2h(f1.y); u[6] = f2h(f1.z); u[7] = f2h(f1.w);
                *(ushortx8*)(&As[r * LDS_STRIDE + col]) = u;
            }
            *(ushortx8*)(&Bs[r * LDS_STRIDE + col]) =
                *(const ushortx8*)(Bb + (size_t)(tileN + r) * ldb + k0 + col);
        }
        __syncthreads();

        half8 aF[4], bF[4];
#pragma unroll
        for (int i = 0; i < 4; i++) {
            aF[i] = *(const half8*)(&As[(wr + i * 16 + lrow) * LDS_STRIDE + kq]);
            bF[i] = *(const half8*)(&Bs[(wc + i * 16 + lrow) * LDS_STRIDE + kq]);
        }
#pragma unroll
        for (int i = 0; i < 4; i++)
#pragma unroll
            for (int j = 0; j < 4; j++)
                acc[i][j] = __builtin_amdgcn_mfma_f32_16x16x32_f16(aF[i], bF[j], acc[i][j], 0, 0, 0);
        __syncthreads();
    }

    // epilogue: C/D layout col=lane&15, row=(lane>>4)*4+reg (dtype-independent)
    const int rq = (lane >> 4) * 4;
#pragma unroll
    for (int i = 0; i < 4; i++) {
#pragma unroll
        for (int j = 0; j < 4; j++) {
            const int gn = tileN + wc + j * 16 + lrow;
            const float bv = HB ? bias[gn] : 0.f;
#pragma unroll
            for (int r = 0; r < 4; r++) {
                const int gm = tileM + wr + i * 16 + rq + r;
                const float val = acc[i][j][r] * scale + bv;
                const size_t idx = TRANS ? ((size_t)gn * ldc + gm) : ((size_t)gm * ldc + gn);
                if (OM == 0) {
                    float* Cf = (float*)C + (size_t)bz * batchC;
                    Cf[idx] = val;
                } else {
                    ushort* Ch = (ushort*)C + (size_t)bz * batchC;
                    Ch[idx] = f2h(val);
                }
            }
        }
    }
}

// fp32 -> fp16 elementwise, 8 elems/thread, n % 2048 == 0
__global__ __launch_bounds__(256)
void cvt_f32_to_f16(const float* __restrict__ src, ushort* __restrict__ dst, int n)
{
    const int i = (blockIdx.x * 256 + threadIdx.x) * 8;
    if (i >= n) return;
    floatx4 f0 = *(const floatx4*)(src + i);
    floatx4 f1 = *(const floatx4*)(src + i + 4);
    ushortx8 u;
    u[0] = f2h(f0.x); u[1] = f2h(f0.y); u[2] = f2h(f0.z); u[3] = f2h(f0.w);
    u[4] = f2h(f1.x); u[5] = f2h(f1.y); u[6] = f2h(f1.z); u[7] = f2h(f1.w);
    *(ushortx8*)(dst + i) = u;
}

// Row softmax over S=2048 pre-scaled fp16 logits; fp32 math; fp16 probs in place.
// All global reads precede the first __syncthreads; writes follow the last.
__global__ __launch_bounds__(256)
void softmax_rows(ushort* __restrict__ scores)
{
    const int S = 2048;
    ushort* srow = scores + (size_t)blockIdx.x * S;
    const int t    = threadIdx.x;
    const int lane = t & 63;
    const int w    = t >> 6;

    ushortx8 raw = *(const ushortx8*)(srow + t * 8);
    float l[8];
#pragma unroll
    for (int i = 0; i < 8; i++) l[i] = h2f(raw[i]);

    float m = l[0];
#pragma unroll
    for (int i = 1; i < 8; i++) m = fmaxf(m, l[i]);
#pragma unroll
    for (int off = 32; off >= 1; off >>= 1) m = fmaxf(m, __shfl_down(m, off));

    __shared__ float redm[4], reds[4];
    if (lane == 0) redm[w] = m;
    __syncthreads();
    m = fmaxf(fmaxf(redm[0], redm[1]), fmaxf(redm[2], redm[3]));

    float e[8], s = 0.f;
#pragma unroll
    for (int i = 0; i < 8; i++) { e[i] = __expf(l[i] - m); s += e[i]; }
#pragma unroll
    for (int off = 32; off >= 1; off >>= 1) s += __shfl_down(s, off);
    if (lane == 0) reds[w] = s;
    __syncthreads();
    s = reds[0] + reds[1] + reds[2] + reds[3];
    const float inv = 1.f / s;

    ushortx8 o;
#pragma unroll
    for (int i = 0; i < 8; i++) o[i] = f2h(e[i] * inv);
    *(ushortx8*)(srow + t * 8) = o;
}

extern "C" void kernel_launch(void* const* d_in, const int* in_sizes, int n_in,
                              void* d_out, int out_size, void* d_ws, size_t ws_size,
                              hipStream_t stream)
{
    const int B = 4, S = 2048, D = 1024;
    const size_t SD = (size_t)B * S * D;   // 8M
    const float* q  = (const float*)d_in[0];
    const float* k  = (const float*)d_in[1];
    const float* v  = (const float*)d_in[2];
    const float* Wq = (const float*)d_in[3];
    const float* bq = (const float*)d_in[4];
    const float* Wk = (const float*)d_in[5];
    const float* bk = (const float*)d_in[6];
    const float* Wv = (const float*)d_in[7];
    const float* bv = (const float*)d_in[8];
    const float* Wo = (const float*)d_in[9];
    const float* bo = (const float*)d_in[10];
    float* out = (float*)d_out;

    // ws (fp16/ushort): q16 16 | k16 16 | qp 16 | kp 16 | sc 32 | W16 x4 8  = 104 MB
    // Overlays: vpt over dead q16 (after qp done); attn over dead k16 (after scores).
    ushort* q16  = (ushort*)d_ws;
    ushort* k16  = q16 + SD;
    ushort* qp   = k16 + SD;
    ushort* kp   = qp  + SD;
    ushort* sc   = kp  + SD;                       // [B][S][S]
    ushort* Wq16 = sc  + (size_t)B * S * S;
    ushort* Wk16 = Wq16 + (size_t)D * D;
    ushort* Wv16 = Wk16 + (size_t)D * D;
    ushort* Wo16 = Wv16 + (size_t)D * D;
    ushort* vpt  = q16;   // per batch [D][S]
    ushort* attn = k16;   // [B*S][D]

    dim3 blk(256);
    cvt_f32_to_f16<<<dim3((int)(SD / 2048)), blk, 0, stream>>>(q, q16, (int)SD);
    cvt_f32_to_f16<<<dim3((int)(SD / 2048)), blk, 0, stream>>>(k, k16, (int)SD);
    cvt_f32_to_f16<<<dim3(D * D / 2048), blk, 0, stream>>>(Wq, Wq16, D * D);
    cvt_f32_to_f16<<<dim3(D * D / 2048), blk, 0, stream>>>(Wk, Wk16, D * D);
    cvt_f32_to_f16<<<dim3(D * D / 2048), blk, 0, stream>>>(Wv, Wv16, D * D);
    cvt_f32_to_f16<<<dim3(D * D / 2048), blk, 0, stream>>>(Wo, Wo16, D * D);

    // qp = q @ Wq^T + bq ; kp = k @ Wk^T + bk   (fp16 out)
    gemm_nt<0, 1, false, true><<<dim3(D / TILE, (B * S) / TILE, 1), blk, 0, stream>>>(
        q16, 0, D, Wq16, 0, D, qp, 0, D, bq, 1.0f, D);
    gemm_nt<0, 1, false, true><<<dim3(D / TILE, (B * S) / TILE, 1), blk, 0, stream>>>(
        k16, 0, D, Wk16, 0, D, kp, 0, D, bk, 1.0f, D);
    // sc = 0.125 * qp @ kp^T   (pre-scaled fp16 logits)
    gemm_nt<0, 1, false, false><<<dim3(S / TILE, S / TILE, B), blk, 0, stream>>>(
        qp, (long long)S * D, D, kp, (long long)S * D, D,
        sc, (long long)S * S, S, nullptr, 0.125f, D);
    // vpt = (v @ Wv^T + bv)^T per batch   (fp32 A cvt in staging; overlays dead q16)
    gemm_nt<1, 1, true, true><<<dim3(D / TILE, S / TILE, B), blk, 0, stream>>>(
        v, (long long)S * D, D, Wv16, 0, D, vpt, (long long)D * S, S, bv, 1.0f, D);
    // probs = softmax(sc) in place
    softmax_rows<<<dim3(B * S), blk, 0, stream>>>(sc);
    // attn = probs @ vp   (overlays dead k16)
    gemm_nt<0, 1, false, false><<<dim3(D / TILE, S / TILE, B), blk, 0, stream>>>(
        sc, (long long)S * S, S, vpt, (long long)D * S, S,
        attn, (long long)S * D, D, nullptr, 1.0f, S);
    // out = attn @ Wo^T + bo   (fp32 out)
    gemm_nt<0, 0, false, true><<<dim3(D / TILE, (B * S) / TILE, 1), blk, 0, stream>>>(
        attn, 0, D, Wo16, 0, D, out, 0, D, bo, 1.0f, D);
}

// Round 5
// 428.215 us; speedup vs baseline: 1.4525x; 1.1299x over previous
//
#include <hip/hip_runtime.h>
#include <hip/hip_fp16.h>

typedef __attribute__((ext_vector_type(8))) _Float16 half8;  // MFMA A/B frag (4 VGPRs)
typedef __attribute__((ext_vector_type(4))) float floatx4;   // MFMA C/D frag
typedef __attribute__((ext_vector_type(8))) ushort ushortx8; // 16B of fp16 bits

#define TILE 128
#define BK 32
// LDS tiles are UNPADDED (stride 32 elems = 64B rows): global_load_lds requires
// contiguous wave-uniform-base + lane*16 destinations. Bank conflicts are broken
// by an XOR chunk swizzle applied on the GLOBAL side of the DMA (see below).

__device__ inline ushort f2h(float f) {
    _Float16 h = (_Float16)f;
    ushort u; __builtin_memcpy(&u, &h, 2); return u;
}
__device__ inline float h2f(ushort u) {
    _Float16 h; __builtin_memcpy(&h, &u, 2);
    return (float)h;
}

// async 16B/lane global->LDS DMA; lds dest = base + lane*16 (implicit)
__device__ inline void async_copy16(const ushort* g, ushort* lds) {
    __builtin_amdgcn_global_load_lds(
        (const __attribute__((address_space(1))) void*)(const void*)g,
        (__attribute__((address_space(3))) void*)(void*)lds,
        16, 0, 0);
}

// C[m][n] = scale * sum_k A[m][k]*B[n][k] (+ bias[n])  -- fp16 NT GEMM, MFMA.
// A,B: fp16 rows. OM: 0 = fp32 store, 1 = fp16 store. TRANS: C[n*ldc+m]. HB: fp32 bias.
// LDS swizzle: row r, chunk j (16B) holds global chunk j ^ ((r>>1)&3).
template<int OM, bool TRANS, bool HB>
__global__ __launch_bounds__(256)
void gemm_nt(const ushort* __restrict__ A, long long batchA, int lda,
             const ushort* __restrict__ B, long long batchB, int ldb,
             void* __restrict__ C, long long batchC, int ldc,
             const float* __restrict__ bias, float scale, int K)
{
    __shared__ ushort As[TILE * 32];
    __shared__ ushort Bs[TILE * 32];

    const int bz    = blockIdx.z;
    const int tileM = blockIdx.y * TILE;
    const int tileN = blockIdx.x * TILE;
    const ushort* Ab = A + (size_t)bz * batchA + (size_t)tileM * lda;
    const ushort* Bb = B + (size_t)bz * batchB + (size_t)tileN * ldb;

    const int t    = threadIdx.x;
    const int lane = t & 63;
    const int wave = t >> 6;
    const int wr   = (wave >> 1) * 64;
    const int wc   = (wave & 1) * 64;
    const int lrow = lane & 15;

    // staging constants: within a 16-row (1024B) DMA block, lane i covers
    // row r0 + i/4, LDS chunk i%4  <=  global chunk (i%4) ^ s(r), s(r)=(r>>1)&3
    const int srow = lane >> 2;
    const int scol = ((lane & 3) ^ ((lane >> 3) & 3)) * 8;
    // fragment-read swizzle: global chunk g=lane>>4 of row R lives at LDS chunk
    // g ^ s(R); s(R) = ((lane&15)>>1)&3 for all fragment rows (wr/i*16 are %16==0)
    const int chunk_sw = (((lane >> 4) ^ ((lane >> 1) & 3))) * 8;

    floatx4 acc[4][4];
#pragma unroll
    for (int i = 0; i < 4; i++)
#pragma unroll
        for (int j = 0; j < 4; j++) acc[i][j] = (floatx4){0.f, 0.f, 0.f, 0.f};

    for (int k0 = 0; k0 < K; k0 += BK) {
        // each wave DMAs rows [wave*32, wave*32+32) of both tiles (4 x 1024B)
#pragma unroll
        for (int h = 0; h < 2; h++) {
            const int r0 = wave * 32 + h * 16;
            async_copy16(Ab + (size_t)(r0 + srow) * lda + k0 + scol, &As[r0 * 32]);
            async_copy16(Bb + (size_t)(r0 + srow) * ldb + k0 + scol, &Bs[r0 * 32]);
        }
        __syncthreads();   // drains vmcnt (DMA) before LDS reads

        half8 aF[4], bF[4];
#pragma unroll
        for (int i = 0; i < 4; i++) {
            aF[i] = *(const half8*)(&As[(wr + i * 16 + lrow) * 32 + chunk_sw]);
            bF[i] = *(const half8*)(&Bs[(wc + i * 16 + lrow) * 32 + chunk_sw]);
        }
#pragma unroll
        for (int i = 0; i < 4; i++)
#pragma unroll
            for (int j = 0; j < 4; j++)
                acc[i][j] = __builtin_amdgcn_mfma_f32_16x16x32_f16(aF[i], bF[j], acc[i][j], 0, 0, 0);
        __syncthreads();
    }

    // epilogue: C/D layout col=lane&15, row=(lane>>4)*4+reg
    const int rq = (lane >> 4) * 4;
#pragma unroll
    for (int i = 0; i < 4; i++) {
#pragma unroll
        for (int j = 0; j < 4; j++) {
            const int gn = tileN + wc + j * 16 + lrow;
            const float bv = HB ? bias[gn] : 0.f;
#pragma unroll
            for (int r = 0; r < 4; r++) {
                const int gm = tileM + wr + i * 16 + rq + r;
                const float val = acc[i][j][r] * scale + bv;
                const size_t idx = TRANS ? ((size_t)gn * ldc + gm) : ((size_t)gm * ldc + gn);
                if (OM == 0) {
                    float* Cf = (float*)C + (size_t)bz * batchC;
                    Cf[idx] = val;
                } else {
                    ushort* Ch = (ushort*)C + (size_t)bz * batchC;
                    Ch[idx] = f2h(val);
                }
            }
        }
    }
}

// fp32 -> fp16 elementwise, 8 elems/thread, n % 2048 == 0
__global__ __launch_bounds__(256)
void cvt_f32_to_f16(const float* __restrict__ src, ushort* __restrict__ dst, int n)
{
    const int i = (blockIdx.x * 256 + threadIdx.x) * 8;
    if (i >= n) return;
    floatx4 f0 = *(const floatx4*)(src + i);
    floatx4 f1 = *(const floatx4*)(src + i + 4);
    ushortx8 u;
    u[0] = f2h(f0.x); u[1] = f2h(f0.y); u[2] = f2h(f0.z); u[3] = f2h(f0.w);
    u[4] = f2h(f1.x); u[5] = f2h(f1.y); u[6] = f2h(f1.z); u[7] = f2h(f1.w);
    *(ushortx8*)(dst + i) = u;
}

// Row softmax over S=2048 pre-scaled fp16 logits; fp32 math; fp16 probs in place.
__global__ __launch_bounds__(256)
void softmax_rows(ushort* __restrict__ scores)
{
    const int S = 2048;
    ushort* srow = scores + (size_t)blockIdx.x * S;
    const int t    = threadIdx.x;
    const int lane = t & 63;
    const int w    = t >> 6;

    ushortx8 raw = *(const ushortx8*)(srow + t * 8);
    float l[8];
#pragma unroll
    for (int i = 0; i < 8; i++) l[i] = h2f(raw[i]);

    float m = l[0];
#pragma unroll
    for (int i = 1; i < 8; i++) m = fmaxf(m, l[i]);
#pragma unroll
    for (int off = 32; off >= 1; off >>= 1) m = fmaxf(m, __shfl_down(m, off));

    __shared__ float redm[4], reds[4];
    if (lane == 0) redm[w] = m;
    __syncthreads();
    m = fmaxf(fmaxf(redm[0], redm[1]), fmaxf(redm[2], redm[3]));

    float e[8], s = 0.f;
#pragma unroll
    for (int i = 0; i < 8; i++) { e[i] = __expf(l[i] - m); s += e[i]; }
#pragma unroll
    for (int off = 32; off >= 1; off >>= 1) s += __shfl_down(s, off);
    if (lane == 0) reds[w] = s;
    __syncthreads();
    s = reds[0] + reds[1] + reds[2] + reds[3];
    const float inv = 1.f / s;

    ushortx8 o;
#pragma unroll
    for (int i = 0; i < 8; i++) o[i] = f2h(e[i] * inv);
    *(ushortx8*)(srow + t * 8) = o;
}

extern "C" void kernel_launch(void* const* d_in, const int* in_sizes, int n_in,
                              void* d_out, int out_size, void* d_ws, size_t ws_size,
                              hipStream_t stream)
{
    const int B = 4, S = 2048, D = 1024;
    const size_t SD = (size_t)B * S * D;   // 8M elems
    const float* q  = (const float*)d_in[0];
    const float* k  = (const float*)d_in[1];
    const float* v  = (const float*)d_in[2];
    const float* Wq = (const float*)d_in[3];
    const float* bq = (const float*)d_in[4];
    const float* Wk = (const float*)d_in[5];
    const float* bk = (const float*)d_in[6];
    const float* Wv = (const float*)d_in[7];
    const float* bv = (const float*)d_in[8];
    const float* Wo = (const float*)d_in[9];
    const float* bo = (const float*)d_in[10];
    float* out = (float*)d_out;

    // ws (ushort/fp16): q16 16 | k16 16 | qp 16 | kp 16 | sc 33.5 | W16 x4 8 MB
    // Overlays: v16 in sc region (dead before scores GEMM writes sc);
    //           vpt over dead q16; attn over dead k16.
    ushort* q16  = (ushort*)d_ws;
    ushort* k16  = q16 + SD;
    ushort* qp   = k16 + SD;
    ushort* kp   = qp  + SD;
    ushort* sc   = kp  + SD;                       // [B][S][S]
    ushort* Wq16 = sc  + (size_t)B * S * S;
    ushort* Wk16 = Wq16 + (size_t)D * D;
    ushort* Wv16 = Wk16 + (size_t)D * D;
    ushort* Wo16 = Wv16 + (size_t)D * D;
    ushort* v16  = sc;    // first 16 MB of sc region
    ushort* vpt  = q16;   // per batch [D][S]
    ushort* attn = k16;   // [B*S][D]

    dim3 blk(256);
    cvt_f32_to_f16<<<dim3((int)(SD / 2048)), blk, 0, stream>>>(q, q16, (int)SD);
    cvt_f32_to_f16<<<dim3((int)(SD / 2048)), blk, 0, stream>>>(k, k16, (int)SD);
    cvt_f32_to_f16<<<dim3((int)(SD / 2048)), blk, 0, stream>>>(v, v16, (int)SD);
    cvt_f32_to_f16<<<dim3(D * D / 2048), blk, 0, stream>>>(Wq, Wq16, D * D);
    cvt_f32_to_f16<<<dim3(D * D / 2048), blk, 0, stream>>>(Wk, Wk16, D * D);
    cvt_f32_to_f16<<<dim3(D * D / 2048), blk, 0, stream>>>(Wv, Wv16, D * D);
    cvt_f32_to_f16<<<dim3(D * D / 2048), blk, 0, stream>>>(Wo, Wo16, D * D);

    // qp = q @ Wq^T + bq ; kp = k @ Wk^T + bk
    gemm_nt<1, false, true><<<dim3(D / TILE, (B * S) / TILE, 1), blk, 0, stream>>>(
        q16, 0, D, Wq16, 0, D, qp, 0, D, bq, 1.0f, D);
    gemm_nt<1, false, true><<<dim3(D / TILE, (B * S) / TILE, 1), blk, 0, stream>>>(
        k16, 0, D, Wk16, 0, D, kp, 0, D, bk, 1.0f, D);
    // vpt = (v @ Wv^T + bv)^T per batch  (q16 dead; v16 dies after this)
    gemm_nt<1, true, true><<<dim3(D / TILE, S / TILE, B), blk, 0, stream>>>(
        v16, (long long)S * D, D, Wv16, 0, D, vpt, (long long)D * S, S, bv, 1.0f, D);
    // sc = 0.125 * qp @ kp^T  (overwrites v16 region - now dead)
    gemm_nt<1, false, false><<<dim3(S / TILE, S / TILE, B), blk, 0, stream>>>(
        qp, (long long)S * D, D, kp, (long long)S * D, D,
        sc, (long long)S * S, S, nullptr, 0.125f, D);
    // probs = softmax(sc) in place
    softmax_rows<<<dim3(B * S), blk, 0, stream>>>(sc);
    // attn = probs @ vp  (k16 dead)
    gemm_nt<1, false, false><<<dim3(D / TILE, S / TILE, B), blk, 0, stream>>>(
        sc, (long long)S * S, S, vpt, (long long)D * S, S,
        attn, (long long)S * D, D, nullptr, 1.0f, S);
    // out = attn @ Wo^T + bo  (fp32 out)
    gemm_nt<0, false, true><<<dim3(D / TILE, (B * S) / TILE, 1), blk, 0, stream>>>(
        attn, 0, D, Wo16, 0, D, out, 0, D, bo, 1.0f, D);
}

// Round 6
// 384.431 us; speedup vs baseline: 1.6179x; 1.1139x over previous
//
#include <hip/hip_runtime.h>
#include <hip/hip_fp16.h>

typedef __attribute__((ext_vector_type(8))) _Float16 half8;  // MFMA A/B frag (4 VGPRs)
typedef __attribute__((ext_vector_type(4))) float floatx4;   // MFMA C/D frag
typedef __attribute__((ext_vector_type(8))) ushort ushortx8; // 16B of fp16 bits

#define TILE 128
#define BK 64
// LDS tiles unpadded: 128 rows x 64 elems (128B rows). global_load_lds needs
// wave-uniform base + lane*16 dests. Bank conflicts broken by XOR chunk swizzle:
// LDS chunk c of row r holds global chunk c ^ (r & 7). Frag reads: 16 lanes
// spread over 8 chunks -> 2-way, free (m136). DMA applies XOR on global side.

__device__ inline ushort f2h(float f) {
    _Float16 h = (_Float16)f;
    ushort u; __builtin_memcpy(&u, &h, 2); return u;
}
__device__ inline float h2f(ushort u) {
    _Float16 h; __builtin_memcpy(&h, &u, 2);
    return (float)h;
}

// async 16B/lane global->LDS DMA; lds dest = base + lane*16 (implicit)
__device__ inline void async_copy16(const ushort* g, ushort* lds) {
    __builtin_amdgcn_global_load_lds(
        (const __attribute__((address_space(1))) void*)(const void*)g,
        (__attribute__((address_space(3))) void*)(void*)lds,
        16, 0, 0);
}

// Core 128x128 NT tile loop, BK=64, fp16 MFMA. A/B pre-offset to tile origin.
// A_F32: A is fp32, converted to fp16 during VGPR staging (ds_write path);
// else A staged by DMA like B.
template<bool A_F32>
__device__ __forceinline__ void gemm_core(const void* __restrict__ A, int lda,
                                          const ushort* __restrict__ B, int ldb,
                                          int K, ushort* As, ushort* Bs,
                                          floatx4 acc[4][4])
{
    const int t    = threadIdx.x;
    const int lane = t & 63;
    const int wave = t >> 6;
    const int wr   = (wave >> 1) * 64;
    const int wc   = (wave & 1) * 64;
    const int lrow = lane & 15;
    const int srow = lane >> 3;                 // 0..7 within an 8-row DMA block
    const int gcol = ((lane & 7) ^ srow) * 8;   // global chunk, XOR-swizzled
    const int c0   = lane >> 4;                 // frag base chunk (k-quad)
    const int sw   = lane & 7;                  // frag row swizzle key

    for (int k0 = 0; k0 < K; k0 += BK) {
#pragma unroll
        for (int h = 0; h < 4; h++) {
            const int r0 = wave * 32 + h * 8;   // 8 rows per 1KB DMA
            if (A_F32) {
                const float* src = (const float*)A + (size_t)(r0 + srow) * lda + k0 + gcol;
                floatx4 f0 = *(const floatx4*)src, f1 = *(const floatx4*)(src + 4);
                ushortx8 u;
                u[0] = f2h(f0.x); u[1] = f2h(f0.y); u[2] = f2h(f0.z); u[3] = f2h(f0.w);
                u[4] = f2h(f1.x); u[5] = f2h(f1.y); u[6] = f2h(f1.z); u[7] = f2h(f1.w);
                *(ushortx8*)(&As[(r0 + srow) * 64 + (lane & 7) * 8]) = u;
            } else {
                async_copy16((const ushort*)A + (size_t)(r0 + srow) * lda + k0 + gcol,
                             &As[r0 * 64]);
            }
            async_copy16(B + (size_t)(r0 + srow) * ldb + k0 + gcol, &Bs[r0 * 64]);
        }
        __syncthreads();

#pragma unroll
        for (int step = 0; step < 2; step++) {
            half8 aF[4], bF[4];
            const int ch = ((4 * step + c0) ^ sw) * 8;
#pragma unroll
            for (int i = 0; i < 4; i++) {
                aF[i] = *(const half8*)(&As[(wr + i * 16 + lrow) * 64 + ch]);
                bF[i] = *(const half8*)(&Bs[(wc + i * 16 + lrow) * 64 + ch]);
            }
#pragma unroll
            for (int i = 0; i < 4; i++)
#pragma unroll
                for (int j = 0; j < 4; j++)
                    acc[i][j] = __builtin_amdgcn_mfma_f32_16x16x32_f16(aF[i], bF[j], acc[i][j], 0, 0, 0);
        }
        __syncthreads();
    }
}

// Epilogue. Cb pre-offset to tile origin (TRANS: +tileN*ldc+tileM else +tileM*ldc+tileN),
// bias pre-offset to tileN. C/D layout: col=lane&15, row=(lane>>4)*4+reg.
template<int OM, bool TRANS, bool HB>
__device__ __forceinline__ void epilogue(floatx4 acc[4][4], void* Cb, int ldc,
                                         const float* bias, float scale)
{
    const int lane = threadIdx.x & 63;
    const int wave = threadIdx.x >> 6;
    const int wr = (wave >> 1) * 64, wc = (wave & 1) * 64;
    const int lrow = lane & 15, rq = (lane >> 4) * 4;
#pragma unroll
    for (int i = 0; i < 4; i++) {
#pragma unroll
        for (int j = 0; j < 4; j++) {
            const int n = wc + j * 16 + lrow;
            const float bv = HB ? bias[n] : 0.f;
#pragma unroll
            for (int r = 0; r < 4; r++) {
                const int m = wr + i * 16 + rq + r;
                const float val = acc[i][j][r] * scale + bv;
                const size_t idx = TRANS ? ((size_t)n * ldc + m) : ((size_t)m * ldc + n);
                if (OM == 0) ((float*)Cb)[idx] = val;
                else         ((ushort*)Cb)[idx] = f2h(val);
            }
        }
    }
}

// Generic fp16 NT GEMM (both operands DMA-staged).
template<int OM, bool TRANS, bool HB>
__global__ __launch_bounds__(256)
void gemm_nt(const ushort* __restrict__ A, long long batchA, int lda,
             const ushort* __restrict__ B, long long batchB, int ldb,
             void* __restrict__ C, long long batchC, int ldc,
             const float* __restrict__ bias, float scale, int K)
{
    __shared__ ushort As[TILE * BK];
    __shared__ ushort Bs[TILE * BK];
    const int bz = blockIdx.z;
    const int tileM = blockIdx.y * TILE, tileN = blockIdx.x * TILE;

    floatx4 acc[4][4];
#pragma unroll
    for (int i = 0; i < 4; i++)
#pragma unroll
        for (int j = 0; j < 4; j++) acc[i][j] = (floatx4){0.f, 0.f, 0.f, 0.f};

    gemm_core<false>(A + (size_t)bz * batchA + (size_t)tileM * lda, lda,
                     B + (size_t)bz * batchB + (size_t)tileN * ldb, ldb,
                     K, As, Bs, acc);

    const size_t coff = TRANS ? ((size_t)tileN * ldc + tileM) : ((size_t)tileM * ldc + tileN);
    void* Cb = (OM == 0) ? (void*)((float*)C + (size_t)bz * batchC + coff)
                         : (void*)((ushort*)C + (size_t)bz * batchC + coff);
    epilogue<OM, TRANS, HB>(acc, Cb, ldc, HB ? bias + tileN : nullptr, scale);
}

// Fused Q/K/V projections, one dispatch. grid (8, 192):
//  y in [0,64): qp = q @ Wq^T + bq        (fp32 A cvt in staging)
//  y in [64,128): kp = k @ Wk^T + bk
//  y in [128,192): vpt_b = (v_b @ Wv^T + bv)^T   (b = (y-128)/16)
__global__ __launch_bounds__(256)
void qkv_proj(const float* __restrict__ q, const float* __restrict__ k,
              const float* __restrict__ v,
              const ushort* __restrict__ Wq, const ushort* __restrict__ Wk,
              const ushort* __restrict__ Wv,
              const float* __restrict__ bq, const float* __restrict__ bk,
              const float* __restrict__ bv,
              ushort* __restrict__ qp, ushort* __restrict__ kp,
              ushort* __restrict__ vpt)
{
    __shared__ ushort As[TILE * BK];
    __shared__ ushort Bs[TILE * BK];
    const int D = 1024, S = 2048;
    const int y = blockIdx.y;
    const int tileN = blockIdx.x * TILE;

    floatx4 acc[4][4];
#pragma unroll
    for (int i = 0; i < 4; i++)
#pragma unroll
        for (int j = 0; j < 4; j++) acc[i][j] = (floatx4){0.f, 0.f, 0.f, 0.f};

    if (y < 128) {           // block-uniform branch
        const bool isQ = (y < 64);
        const int my = isQ ? y : y - 64;
        const float* A  = (isQ ? q : k) + (size_t)my * TILE * D;
        const ushort* W = (isQ ? Wq : Wk) + (size_t)tileN * D;
        gemm_core<true>(A, D, W, D, D, As, Bs, acc);
        ushort* Cb = (isQ ? qp : kp) + (size_t)my * TILE * D + tileN;
        epilogue<1, false, true>(acc, Cb, D, (isQ ? bq : bk) + tileN, 1.0f);
    } else {
        const int yy = y - 128;
        const int bz = yy >> 4, my = yy & 15;
        const float* A = v + ((size_t)bz * S + (size_t)my * TILE) * D;
        gemm_core<true>(A, D, Wv + (size_t)tileN * D, D, D, As, Bs, acc);
        ushort* Cb = vpt + (size_t)bz * D * S + (size_t)tileN * S + (size_t)my * TILE;
        epilogue<1, true, true>(acc, Cb, S, bv + tileN, 1.0f);
    }
}

// fp32 -> fp16 for the 4 weight matrices (D*D each); grid (512, 4)
__global__ __launch_bounds__(256)
void cvt_w(const float* __restrict__ w0, const float* __restrict__ w1,
           const float* __restrict__ w2, const float* __restrict__ w3,
           ushort* __restrict__ o0, ushort* __restrict__ o1,
           ushort* __restrict__ o2, ushort* __restrict__ o3)
{
    const float* src; ushort* dst;
    switch (blockIdx.y) {
        case 0: src = w0; dst = o0; break;
        case 1: src = w1; dst = o1; break;
        case 2: src = w2; dst = o2; break;
        default: src = w3; dst = o3; break;
    }
    const size_t i = ((size_t)blockIdx.x * 256 + threadIdx.x) * 8;
    floatx4 f0 = *(const floatx4*)(src + i);
    floatx4 f1 = *(const floatx4*)(src + i + 4);
    ushortx8 u;
    u[0] = f2h(f0.x); u[1] = f2h(f0.y); u[2] = f2h(f0.z); u[3] = f2h(f0.w);
    u[4] = f2h(f1.x); u[5] = f2h(f1.y); u[6] = f2h(f1.z); u[7] = f2h(f1.w);
    *(ushortx8*)(dst + i) = u;
}

// Row softmax over S=2048 pre-scaled fp16 logits; fp32 math; fp16 probs in place.
__global__ __launch_bounds__(256)
void softmax_rows(ushort* __restrict__ scores)
{
    const int S = 2048;
    ushort* srow = scores + (size_t)blockIdx.x * S;
    const int t    = threadIdx.x;
    const int lane = t & 63;
    const int w    = t >> 6;

    ushortx8 raw = *(const ushortx8*)(srow + t * 8);
    float l[8];
#pragma unroll
    for (int i = 0; i < 8; i++) l[i] = h2f(raw[i]);

    float m = l[0];
#pragma unroll
    for (int i = 1; i < 8; i++) m = fmaxf(m, l[i]);
#pragma unroll
    for (int off = 32; off >= 1; off >>= 1) m = fmaxf(m, __shfl_down(m, off));

    __shared__ float redm[4], reds[4];
    if (lane == 0) redm[w] = m;
    __syncthreads();
    m = fmaxf(fmaxf(redm[0], redm[1]), fmaxf(redm[2], redm[3]));

    float e[8], s = 0.f;
#pragma unroll
    for (int i = 0; i < 8; i++) { e[i] = __expf(l[i] - m); s += e[i]; }
#pragma unroll
    for (int off = 32; off >= 1; off >>= 1) s += __shfl_down(s, off);
    if (lane == 0) reds[w] = s;
    __syncthreads();
    s = reds[0] + reds[1] + reds[2] + reds[3];
    const float inv = 1.f / s;

    ushortx8 o;
#pragma unroll
    for (int i = 0; i < 8; i++) o[i] = f2h(e[i] * inv);
    *(ushortx8*)(srow + t * 8) = o;
}

extern "C" void kernel_launch(void* const* d_in, const int* in_sizes, int n_in,
                              void* d_out, int out_size, void* d_ws, size_t ws_size,
                              hipStream_t stream)
{
    const int B = 4, S = 2048, D = 1024;
    const size_t SD = (size_t)B * S * D;   // 8M elems
    const float* q  = (const float*)d_in[0];
    const float* k  = (const float*)d_in[1];
    const float* v  = (const float*)d_in[2];
    const float* Wq = (const float*)d_in[3];
    const float* bq = (const float*)d_in[4];
    const float* Wk = (const float*)d_in[5];
    const float* bk = (const float*)d_in[6];
    const float* Wv = (const float*)d_in[7];
    const float* bv = (const float*)d_in[8];
    const float* Wo = (const float*)d_in[9];
    const float* bo = (const float*)d_in[10];
    float* out = (float*)d_out;

    // ws (ushort): qp 16MB | kp 16MB | sc 33.5MB | W16 x4 8MB | vpt 16MB | attn 16MB = 105.5MB
    ushort* qp   = (ushort*)d_ws;
    ushort* kp   = qp + SD;
    ushort* sc   = kp + SD;                        // [B][S][S]
    ushort* Wq16 = sc + (size_t)B * S * S;
    ushort* Wk16 = Wq16 + (size_t)D * D;
    ushort* Wv16 = Wk16 + (size_t)D * D;
    ushort* Wo16 = Wv16 + (size_t)D * D;
    ushort* vpt  = Wo16 + (size_t)D * D;           // per batch [D][S]
    ushort* attn = vpt + SD;                       // [B*S][D]

    dim3 blk(256);

    cvt_w<<<dim3(D * D / 2048, 4), blk, 0, stream>>>(Wq, Wk, Wv, Wo, Wq16, Wk16, Wv16, Wo16);

    // qp/kp/vpt in one dispatch (fp32 inputs cvt'd in staging)
    qkv_proj<<<dim3(D / TILE, 192), blk, 0, stream>>>(
        q, k, v, Wq16, Wk16, Wv16, bq, bk, bv, qp, kp, vpt);

    // sc = 0.125 * qp @ kp^T  (pre-scaled fp16 logits)
    gemm_nt<1, false, false><<<dim3(S / TILE, S / TILE, B), blk, 0, stream>>>(
        qp, (long long)S * D, D, kp, (long long)S * D, D,
        sc, (long long)S * S, S, nullptr, 0.125f, D);

    softmax_rows<<<dim3(B * S), blk, 0, stream>>>(sc);

    // attn = probs @ vp  (vp given as vpt rows)
    gemm_nt<1, false, false><<<dim3(D / TILE, S / TILE, B), blk, 0, stream>>>(
        sc, (long long)S * S, S, vpt, (long long)D * S, S,
        attn, (long long)S * D, D, nullptr, 1.0f, S);

    // out = attn @ Wo^T + bo  (fp32 out)
    gemm_nt<0, false, true><<<dim3(D / TILE, (B * S) / TILE, 1), blk, 0, stream>>>(
        attn, 0, D, Wo16, 0, D, out, 0, D, bo, 1.0f, D);
}

// Round 7
// 369.414 us; speedup vs baseline: 1.6837x; 1.0407x over previous
//
#include <hip/hip_runtime.h>
#include <hip/hip_fp16.h>

typedef __attribute__((ext_vector_type(8))) _Float16 half8;  // MFMA A/B frag (4 VGPRs)
typedef __attribute__((ext_vector_type(4))) float floatx4;   // MFMA C/D frag
typedef __attribute__((ext_vector_type(8))) ushort ushortx8; // 16B of fp16 bits

#define TILE 128
#define BK 64
// LDS tiles unpadded: 128 rows x 64 elems (128B rows). global_load_lds needs
// wave-uniform base + lane*16 dests. Bank conflicts broken by XOR chunk swizzle:
// LDS chunk c of row r holds global chunk c ^ (r & 7). Frag reads: 16 lanes
// spread over 8 chunks -> 2-way, free (m136). DMA applies XOR on global side.

__device__ inline ushort f2h(float f) {
    _Float16 h = (_Float16)f;
    ushort u; __builtin_memcpy(&u, &h, 2); return u;
}
__device__ inline float h2f(ushort u) {
    _Float16 h; __builtin_memcpy(&h, &u, 2);
    return (float)h;
}

// async 16B/lane global->LDS DMA; lds dest = base + lane*16 (implicit)
__device__ inline void async_copy16(const ushort* g, ushort* lds) {
    __builtin_amdgcn_global_load_lds(
        (const __attribute__((address_space(1))) void*)(const void*)g,
        (__attribute__((address_space(3))) void*)(void*)lds,
        16, 0, 0);
}

// XCD-aware remap (8 XCDs, flat id dispatched x-fastest, XCD = flat % 8
// round-robin heuristic). Groups all X blocks of a y-row onto ONE XCD with
// consecutive issue order, so row-shared A tiles are fetched into L2 once.
// Pure permutation: correctness-neutral if the placement assumption is wrong.
__device__ inline void xcd_swizzle(int X, int YZ, int& bx, int& yz) {
    if ((YZ & 7) != 0) return;           // need YZ % 8 == 0
    const int flat = yz * X + bx;
    const int xcd  = flat & 7;
    const int t    = flat >> 3;          // rank within this XCD
    const int rows = YZ >> 3;            // y-rows per XCD
    yz = xcd * rows + t / X;
    bx = t % X;
}

// Core 128x128 NT tile loop, BK=64, fp16 MFMA. A/B pre-offset to tile origin.
// A_F32: A is fp32, converted to fp16 during VGPR staging (ds_write path);
// else A staged by DMA like B.
template<bool A_F32>
__device__ __forceinline__ void gemm_core(const void* __restrict__ A, int lda,
                                          const ushort* __restrict__ B, int ldb,
                                          int K, ushort* As, ushort* Bs,
                                          floatx4 acc[4][4])
{
    const int t    = threadIdx.x;
    const int lane = t & 63;
    const int wave = t >> 6;
    const int wr   = (wave >> 1) * 64;
    const int wc   = (wave & 1) * 64;
    const int lrow = lane & 15;
    const int srow = lane >> 3;                 // 0..7 within an 8-row DMA block
    const int gcol = ((lane & 7) ^ srow) * 8;   // global chunk, XOR-swizzled
    const int c0   = lane >> 4;                 // frag base chunk (k-quad)
    const int sw   = lane & 7;                  // frag row swizzle key

    for (int k0 = 0; k0 < K; k0 += BK) {
#pragma unroll
        for (int h = 0; h < 4; h++) {
            const int r0 = wave * 32 + h * 8;   // 8 rows per 1KB DMA
            if (A_F32) {
                const float* src = (const float*)A + (size_t)(r0 + srow) * lda + k0 + gcol;
                floatx4 f0 = *(const floatx4*)src, f1 = *(const floatx4*)(src + 4);
                ushortx8 u;
                u[0] = f2h(f0.x); u[1] = f2h(f0.y); u[2] = f2h(f0.z); u[3] = f2h(f0.w);
                u[4] = f2h(f1.x); u[5] = f2h(f1.y); u[6] = f2h(f1.z); u[7] = f2h(f1.w);
                *(ushortx8*)(&As[(r0 + srow) * 64 + (lane & 7) * 8]) = u;
            } else {
                async_copy16((const ushort*)A + (size_t)(r0 + srow) * lda + k0 + gcol,
                             &As[r0 * 64]);
            }
            async_copy16(B + (size_t)(r0 + srow) * ldb + k0 + gcol, &Bs[r0 * 64]);
        }
        __syncthreads();

#pragma unroll
        for (int step = 0; step < 2; step++) {
            half8 aF[4], bF[4];
            const int ch = ((4 * step + c0) ^ sw) * 8;
#pragma unroll
            for (int i = 0; i < 4; i++) {
                aF[i] = *(const half8*)(&As[(wr + i * 16 + lrow) * 64 + ch]);
                bF[i] = *(const half8*)(&Bs[(wc + i * 16 + lrow) * 64 + ch]);
            }
#pragma unroll
            for (int i = 0; i < 4; i++)
#pragma unroll
                for (int j = 0; j < 4; j++)
                    acc[i][j] = __builtin_amdgcn_mfma_f32_16x16x32_f16(aF[i], bF[j], acc[i][j], 0, 0, 0);
        }
        __syncthreads();
    }
}

// Epilogue. Cb pre-offset to tile origin; bias pre-offset to tileN.
// C/D layout: col=lane&15, row=(lane>>4)*4+reg.
template<int OM, bool TRANS, bool HB>
__device__ __forceinline__ void epilogue(floatx4 acc[4][4], void* Cb, int ldc,
                                         const float* bias, float scale)
{
    const int lane = threadIdx.x & 63;
    const int wave = threadIdx.x >> 6;
    const int wr = (wave >> 1) * 64, wc = (wave & 1) * 64;
    const int lrow = lane & 15, rq = (lane >> 4) * 4;
#pragma unroll
    for (int i = 0; i < 4; i++) {
#pragma unroll
        for (int j = 0; j < 4; j++) {
            const int n = wc + j * 16 + lrow;
            const float bv = HB ? bias[n] : 0.f;
#pragma unroll
            for (int r = 0; r < 4; r++) {
                const int m = wr + i * 16 + rq + r;
                const float val = acc[i][j][r] * scale + bv;
                const size_t idx = TRANS ? ((size_t)n * ldc + m) : ((size_t)m * ldc + n);
                if (OM == 0) ((float*)Cb)[idx] = val;
                else         ((ushort*)Cb)[idx] = f2h(val);
            }
        }
    }
}

// Generic fp16 NT GEMM (both operands DMA-staged), XCD-swizzled.
template<int OM, bool TRANS, bool HB>
__global__ __launch_bounds__(256)
void gemm_nt(const ushort* __restrict__ A, long long batchA, int lda,
             const ushort* __restrict__ B, long long batchB, int ldb,
             void* __restrict__ C, long long batchC, int ldc,
             const float* __restrict__ bias, float scale, int K)
{
    __shared__ ushort As[TILE * BK];
    __shared__ ushort Bs[TILE * BK];

    int bx = blockIdx.x;
    int yz = blockIdx.y + gridDim.y * blockIdx.z;
    xcd_swizzle(gridDim.x, gridDim.y * gridDim.z, bx, yz);
    const int by = yz % gridDim.y;
    const int bz = yz / gridDim.y;
    const int tileM = by * TILE, tileN = bx * TILE;

    floatx4 acc[4][4];
#pragma unroll
    for (int i = 0; i < 4; i++)
#pragma unroll
        for (int j = 0; j < 4; j++) acc[i][j] = (floatx4){0.f, 0.f, 0.f, 0.f};

    gemm_core<false>(A + (size_t)bz * batchA + (size_t)tileM * lda, lda,
                     B + (size_t)bz * batchB + (size_t)tileN * ldb, ldb,
                     K, As, Bs, acc);

    const size_t coff = TRANS ? ((size_t)tileN * ldc + tileM) : ((size_t)tileM * ldc + tileN);
    void* Cb = (OM == 0) ? (void*)((float*)C + (size_t)bz * batchC + coff)
                         : (void*)((ushort*)C + (size_t)bz * batchC + coff);
    epilogue<OM, TRANS, HB>(acc, Cb, ldc, HB ? bias + tileN : nullptr, scale);
}

// Fused Q/K/V projections, one dispatch. logical grid (8, 192), XCD-swizzled:
//  y in [0,64): qp = q @ Wq^T + bq        (fp32 A cvt in staging)
//  y in [64,128): kp = k @ Wk^T + bk
//  y in [128,192): vpt_b = (v_b @ Wv^T + bv)^T   (b = (y-128)/16)
__global__ __launch_bounds__(256)
void qkv_proj(const float* __restrict__ q, const float* __restrict__ k,
              const float* __restrict__ v,
              const ushort* __restrict__ Wq, const ushort* __restrict__ Wk,
              const ushort* __restrict__ Wv,
              const float* __restrict__ bq, const float* __restrict__ bk,
              const float* __restrict__ bv,
              ushort* __restrict__ qp, ushort* __restrict__ kp,
              ushort* __restrict__ vpt)
{
    __shared__ ushort As[TILE * BK];
    __shared__ ushort Bs[TILE * BK];
    const int D = 1024, S = 2048;

    int bx = blockIdx.x, y = blockIdx.y;
    xcd_swizzle(8, 192, bx, y);
    const int tileN = bx * TILE;

    floatx4 acc[4][4];
#pragma unroll
    for (int i = 0; i < 4; i++)
#pragma unroll
        for (int j = 0; j < 4; j++) acc[i][j] = (floatx4){0.f, 0.f, 0.f, 0.f};

    if (y < 128) {           // block-uniform branch
        const bool isQ = (y < 64);
        const int my = isQ ? y : y - 64;
        const float* A  = (isQ ? q : k) + (size_t)my * TILE * D;
        const ushort* W = (isQ ? Wq : Wk) + (size_t)tileN * D;
        gemm_core<true>(A, D, W, D, D, As, Bs, acc);
        ushort* Cb = (isQ ? qp : kp) + (size_t)my * TILE * D + tileN;
        epilogue<1, false, true>(acc, Cb, D, (isQ ? bq : bk) + tileN, 1.0f);
    } else {
        const int yy = y - 128;
        const int bz = yy >> 4, my = yy & 15;
        const float* A = v + ((size_t)bz * S + (size_t)my * TILE) * D;
        gemm_core<true>(A, D, Wv + (size_t)tileN * D, D, D, As, Bs, acc);
        ushort* Cb = vpt + (size_t)bz * D * S + (size_t)tileN * S + (size_t)my * TILE;
        epilogue<1, true, true>(acc, Cb, S, bv + tileN, 1.0f);
    }
}

// fp32 -> fp16 for the 4 weight matrices (D*D each); grid (512, 4)
__global__ __launch_bounds__(256)
void cvt_w(const float* __restrict__ w0, const float* __restrict__ w1,
           const float* __restrict__ w2, const float* __restrict__ w3,
           ushort* __restrict__ o0, ushort* __restrict__ o1,
           ushort* __restrict__ o2, ushort* __restrict__ o3)
{
    const float* src; ushort* dst;
    switch (blockIdx.y) {
        case 0: src = w0; dst = o0; break;
        case 1: src = w1; dst = o1; break;
        case 2: src = w2; dst = o2; break;
        default: src = w3; dst = o3; break;
    }
    const size_t i = ((size_t)blockIdx.x * 256 + threadIdx.x) * 8;
    floatx4 f0 = *(const floatx4*)(src + i);
    floatx4 f1 = *(const floatx4*)(src + i + 4);
    ushortx8 u;
    u[0] = f2h(f0.x); u[1] = f2h(f0.y); u[2] = f2h(f0.z); u[3] = f2h(f0.w);
    u[4] = f2h(f1.x); u[5] = f2h(f1.y); u[6] = f2h(f1.z); u[7] = f2h(f1.w);
    *(ushortx8*)(dst + i) = u;
}

// Row softmax over S=2048 pre-scaled fp16 logits; fp32 math; fp16 probs in place.
__global__ __launch_bounds__(256)
void softmax_rows(ushort* __restrict__ scores)
{
    const int S = 2048;
    ushort* srow = scores + (size_t)blockIdx.x * S;
    const int t    = threadIdx.x;
    const int lane = t & 63;
    const int w    = t >> 6;

    ushortx8 raw = *(const ushortx8*)(srow + t * 8);
    float l[8];
#pragma unroll
    for (int i = 0; i < 8; i++) l[i] = h2f(raw[i]);

    float m = l[0];
#pragma unroll
    for (int i = 1; i < 8; i++) m = fmaxf(m, l[i]);
#pragma unroll
    for (int off = 32; off >= 1; off >>= 1) m = fmaxf(m, __shfl_down(m, off));

    __shared__ float redm[4], reds[4];
    if (lane == 0) redm[w] = m;
    __syncthreads();
    m = fmaxf(fmaxf(redm[0], redm[1]), fmaxf(redm[2], redm[3]));

    float e[8], s = 0.f;
#pragma unroll
    for (int i = 0; i < 8; i++) { e[i] = __expf(l[i] - m); s += e[i]; }
#pragma unroll
    for (int off = 32; off >= 1; off >>= 1) s += __shfl_down(s, off);
    if (lane == 0) reds[w] = s;
    __syncthreads();
    s = reds[0] + reds[1] + reds[2] + reds[3];
    const float inv = 1.f / s;

    ushortx8 o;
#pragma unroll
    for (int i = 0; i < 8; i++) o[i] = f2h(e[i] * inv);
    *(ushortx8*)(srow + t * 8) = o;
}

extern "C" void kernel_launch(void* const* d_in, const int* in_sizes, int n_in,
                              void* d_out, int out_size, void* d_ws, size_t ws_size,
                              hipStream_t stream)
{
    const int B = 4, S = 2048, D = 1024;
    const size_t SD = (size_t)B * S * D;   // 8M elems
    const float* q  = (const float*)d_in[0];
    const float* k  = (const float*)d_in[1];
    const float* v  = (const float*)d_in[2];
    const float* Wq = (const float*)d_in[3];
    const float* bq = (const float*)d_in[4];
    const float* Wk = (const float*)d_in[5];
    const float* bk = (const float*)d_in[6];
    const float* Wv = (const float*)d_in[7];
    const float* bv = (const float*)d_in[8];
    const float* Wo = (const float*)d_in[9];
    const float* bo = (const float*)d_in[10];
    float* out = (float*)d_out;

    // ws (ushort): qp 16MB | kp 16MB | sc 33.5MB | W16 x4 8MB | vpt 16MB | attn 16MB = 105.5MB
    ushort* qp   = (ushort*)d_ws;
    ushort* kp   = qp + SD;
    ushort* sc   = kp + SD;                        // [B][S][S]
    ushort* Wq16 = sc + (size_t)B * S * S;
    ushort* Wk16 = Wq16 + (size_t)D * D;
    ushort* Wv16 = Wk16 + (size_t)D * D;
    ushort* Wo16 = Wv16 + (size_t)D * D;
    ushort* vpt  = Wo16 + (size_t)D * D;           // per batch [D][S]
    ushort* attn = vpt + SD;                       // [B*S][D]

    dim3 blk(256);

    cvt_w<<<dim3(D * D / 2048, 4), blk, 0, stream>>>(Wq, Wk, Wv, Wo, Wq16, Wk16, Wv16, Wo16);

    // qp/kp/vpt in one dispatch (fp32 inputs cvt'd in staging)
    qkv_proj<<<dim3(D / TILE, 192), blk, 0, stream>>>(
        q, k, v, Wq16, Wk16, Wv16, bq, bk, bv, qp, kp, vpt);

    // sc = 0.125 * qp @ kp^T  (pre-scaled fp16 logits)
    gemm_nt<1, false, false><<<dim3(S / TILE, S / TILE, B), blk, 0, stream>>>(
        qp, (long long)S * D, D, kp, (long long)S * D, D,
        sc, (long long)S * S, S, nullptr, 0.125f, D);

    softmax_rows<<<dim3(B * S), blk, 0, stream>>>(sc);

    // attn = probs @ vp  (vp given as vpt rows)
    gemm_nt<1, false, false><<<dim3(D / TILE, S / TILE, B), blk, 0, stream>>>(
        sc, (long long)S * S, S, vpt, (long long)D * S, S,
        attn, (long long)S * D, D, nullptr, 1.0f, S);

    // out = attn @ Wo^T + bo  (fp32 out)
    gemm_nt<0, false, true><<<dim3(D / TILE, (B * S) / TILE, 1), blk, 0, stream>>>(
        attn, 0, D, Wo16, 0, D, out, 0, D, bo, 1.0f, D);
}